// Round 2
// baseline (197.943 us; speedup 1.0000x reference)
//
#include <hip/hip_runtime.h>
#include <hip/hip_bf16.h>

#define LN_EPS 1e-5f

static __device__ __forceinline__ float readlane_f(float v, int lane) {
    return __int_as_float(__builtin_amdgcn_readlane(__float_as_int(v), lane));
}

// ---------------------------------------------------------------------------
// Kernel A: per-token-id key table. key[v] = LN(e_v + FF(e_v)), v in [0,64).
// 64 blocks (one per token id) x 64 threads (one wave).
// ---------------------------------------------------------------------------
__global__ __launch_bounds__(64) void build_keys(
    const float* __restrict__ embed,   // 64x64
    const float* __restrict__ w1,      // 64x128
    const float* __restrict__ b1,      // 128
    const float* __restrict__ w2,      // 128x64
    const float* __restrict__ b2,      // 64
    const float* __restrict__ lnw,     // 64
    const float* __restrict__ lnb,     // 64
    float* __restrict__ keytab)        // 64x64 out
{
    const int v = blockIdx.x, lane = threadIdx.x;
    __shared__ float se[64];
    __shared__ float sh[128];
    se[lane] = embed[v * 64 + lane];
    __syncthreads();
    float h0 = b1[lane];
    float h1 = b1[lane + 64];
    #pragma unroll 8
    for (int i = 0; i < 64; ++i) {
        float e = se[i];
        h0 = fmaf(e, w1[i * 128 + lane], h0);
        h1 = fmaf(e, w1[i * 128 + lane + 64], h1);
    }
    sh[lane]      = fmaxf(h0, 0.f);
    sh[lane + 64] = fmaxf(h1, 0.f);
    __syncthreads();
    float acc = b2[lane];
    #pragma unroll 8
    for (int j = 0; j < 128; ++j)
        acc = fmaf(sh[j], w2[j * 64 + lane], acc);
    float pre = se[lane] + acc;
    // LayerNorm across the 64 lanes (one wave)
    float sum = pre;
    #pragma unroll
    for (int off = 32; off >= 1; off >>= 1) sum += __shfl_xor(sum, off, 64);
    float mu  = sum * (1.f / 64.f);
    float dev = pre - mu;
    float sq  = dev * dev;
    #pragma unroll
    for (int off = 32; off >= 1; off >>= 1) sq += __shfl_xor(sq, off, 64);
    float var = sq * (1.f / 64.f);
    float key = dev * (1.f / sqrtf(var + LN_EPS)) * lnw[lane] + lnb[lane];
    keytab[v * 64 + lane] = key;
}

// ---------------------------------------------------------------------------
// Kernel B: Gram tables + fused output weight.
//   G[w][u]    = key_w . key_u            (symmetric)
//   Ghat[w][u] = G[w][u] / (G[w][w]+1e-6)
//   Wc[i][o]   = sum_j read_w[i][j] * out_w[j][o]
//   bias[o]    = sum_j read_b[j]   * out_w[j][o] + out_b[o]
// 64 blocks x 64 threads; block w computes row w.
// ---------------------------------------------------------------------------
__global__ __launch_bounds__(64) void build_tables(
    const float* __restrict__ keytab,
    const float* __restrict__ read_w,
    const float* __restrict__ read_b,
    const float* __restrict__ out_w,
    const float* __restrict__ out_b,
    float* __restrict__ Gg,
    float* __restrict__ Ghat,
    float* __restrict__ Wc,
    float* __restrict__ biasv)
{
    const int w = blockIdx.x, lane = threadIdx.x;
    __shared__ float sk[64 * 65];   // +1 pad: conflict-free strided dot reads
    __shared__ float srw[64];
    #pragma unroll 8
    for (int r = 0; r < 64; ++r) sk[r * 65 + lane] = keytab[r * 64 + lane];
    srw[lane] = read_w[w * 64 + lane];
    __syncthreads();
    float g = 0.f;
    #pragma unroll 8
    for (int i = 0; i < 64; ++i)
        g = fmaf(sk[w * 65 + i], sk[lane * 65 + i], g);
    float gww  = readlane_f(g, w);              // G[w][w] (w is uniform)
    float beta = 1.f / (gww + 1e-6f);
    Gg[w * 64 + lane]   = g;
    Ghat[w * 64 + lane] = beta * g;
    float acc = 0.f;
    #pragma unroll 8
    for (int j = 0; j < 64; ++j)
        acc = fmaf(srw[j], out_w[j * 64 + lane], acc);
    Wc[w * 64 + lane] = acc;
    if (w == 0) {
        float bacc = out_b[lane];
        #pragma unroll 8
        for (int j = 0; j < 64; ++j)
            bacc = fmaf(read_b[j], out_w[j * 64 + lane], bacc);
        biasv[lane] = bacc;
    }
}

// ---------------------------------------------------------------------------
// Kernel C: dual-space backward delta scan. One wave per batch.
// d_v = k_v . z   (lane = v).  Backward over t = 4094..0:
//   s_t = d[w_t];  c[w_t] += s_t;  d -= s_t * Ghat[w_t][:]
// One-step-stale readlane + scalar correction keeps the critical chain at
// one FMA/step; depth-9 LDS prefetch queue hides ds_read latency.
// 65 blocks of 63 steps each (65*63 = 4095), seq prefetched a block ahead.
// ---------------------------------------------------------------------------
__global__ __launch_bounds__(64) void delta_scan(
    const int*   __restrict__ seq,     // B x 4096
    const float* __restrict__ Gg,      // 64x64
    const float* __restrict__ Ghat,    // 64x64
    const float* __restrict__ keytab,  // 64x64
    const float* __restrict__ Wc,      // 64x64
    const float* __restrict__ biasv,   // 64
    float* __restrict__ out)           // B x 64
{
    const int lane = threadIdx.x;
    const int b    = blockIdx.x;
    __shared__ float sG[64 * 64];   // Ghat rows; lane-consecutive reads (2-way alias = free)
    __shared__ float sC[64];
    __shared__ float sCtx[64];
    #pragma unroll 8
    for (int r = 0; r < 64; ++r) sG[r * 64 + lane] = Ghat[r * 64 + lane];
    const int* seqb = seq + (size_t)b * 4096;
    const int wq = seqb[4095];                 // query token id
    float d = Gg[wq * 64 + lane];              // d_v = k_v . q = G[wq][v]
    __syncthreads();

    float c = 0.f, s1 = 0.f, gh1 = 0.f;
    int vcur = seqb[64 * 63 + lane];           // top block: t = 4032+lane
    float q_[9];                               // in-flight Ghat rows, depth 9 (63 % 9 == 0)
    #pragma unroll
    for (int m = 0; m < 9; ++m) {
        int w = __builtin_amdgcn_readlane(vcur, 62 - m);   // w_{4094-m}
        q_[m] = sG[w * 64 + lane];
    }
    for (int blk = 64; blk >= 0; --blk) {
        int vnext = (blk > 0) ? seqb[(blk - 1) * 63 + lane] : vcur;
        #pragma unroll
        for (int j = 62; j >= 0; --j) {        // t = blk*63 + j, descending
            const int slot = (62 - j) % 9;
            int   w0 = __builtin_amdgcn_readlane(vcur, j);
            float p  = readlane_f(d, w0);      // d one-step-stale at lane w0
            float g  = readlane_f(gh1, w0);    // Ghat[w_{t+1}][w_t]
            float s0 = fmaf(-s1, g, p);        // exact s_t (same rounding as in-order)
            d = fmaf(-s1, gh1, d);             // apply deferred step-(t+1) update
            c += (lane == w0) ? s0 : 0.f;      // c_{w_t} += s_t
            float rown = q_[slot];             // Ghat[w_t][:], loaded 9 iters ago
            int jl = j - 9;                    // prefetch row for step t-9
            int wpre = (jl >= 0) ? __builtin_amdgcn_readlane(vcur, jl)
                                 : __builtin_amdgcn_readlane(vnext, jl + 63);
            q_[slot] = sG[wpre * 64 + lane];
            s1 = s0; gh1 = rown;
        }
        vcur = vnext;
    }

    // ctx = sum_v c_v * key_v ; out = ctx @ Wc + bias
    sC[lane] = c;
    __syncthreads();
    float ctx = 0.f;
    #pragma unroll 8
    for (int v = 0; v < 64; ++v)
        ctx = fmaf(sC[v], keytab[v * 64 + lane], ctx);
    sCtx[lane] = ctx;
    __syncthreads();
    float o = biasv[lane];
    #pragma unroll 8
    for (int i = 0; i < 64; ++i)
        o = fmaf(sCtx[i], Wc[i * 64 + lane], o);
    out[(size_t)b * 64 + lane] = o;
}

extern "C" void kernel_launch(void* const* d_in, const int* in_sizes, int n_in,
                              void* d_out, int out_size, void* d_ws, size_t ws_size,
                              hipStream_t stream) {
    const int*   seq    = (const int*)d_in[0];
    const float* embed  = (const float*)d_in[1];
    const float* ff_w1  = (const float*)d_in[2];
    const float* ff_b1  = (const float*)d_in[3];
    const float* ff_w2  = (const float*)d_in[4];
    const float* ff_b2  = (const float*)d_in[5];
    const float* ln_w   = (const float*)d_in[6];
    const float* ln_b   = (const float*)d_in[7];
    const float* read_w = (const float*)d_in[8];
    const float* read_b = (const float*)d_in[9];
    const float* out_w  = (const float*)d_in[10];
    const float* out_b  = (const float*)d_in[11];
    float* out = (float*)d_out;

    float* wsf    = (float*)d_ws;
    float* keytab = wsf;            // 4096
    float* Gg     = wsf + 4096;     // 4096
    float* Ghat   = wsf + 8192;     // 4096
    float* Wc     = wsf + 12288;    // 4096
    float* biasv  = wsf + 16384;    // 64

    build_keys<<<64, 64, 0, stream>>>(embed, ff_w1, ff_b1, ff_w2, ff_b2, ln_w, ln_b, keytab);
    build_tables<<<64, 64, 0, stream>>>(keytab, read_w, read_b, out_w, out_b,
                                        Gg, Ghat, Wc, biasv);
    delta_scan<<<256, 64, 0, stream>>>(seq, Gg, Ghat, keytab, Wc, biasv, out);
}